// Round 14
// baseline (799.551 us; speedup 1.0000x reference)
//
#include <hip/hip_runtime.h>
#include <hip/hip_bf16.h>
#include <math.h>

#define D 256
#define EPS 1e-5f
#define SCAN_NB 256

typedef _Float16 f16;
typedef _Float16 f16x2 __attribute__((ext_vector_type(2)));
typedef _Float16 f16x4 __attribute__((ext_vector_type(4)));
typedef _Float16 f16x8 __attribute__((ext_vector_type(8)));
typedef float f32x4v __attribute__((ext_vector_type(4)));

// ---------------------------------------------------------------- CSR build
__global__ void k_count(const int* __restrict__ dst, int* __restrict__ cnt, int E) {
    int e = blockIdx.x * blockDim.x + threadIdx.x;
    if (e < E) atomicAdd(&cnt[dst[e]], 1);
}

__global__ void k_scan_part(const int* __restrict__ cnt, int* __restrict__ row_ptr,
                            int* __restrict__ partial, int N, int C) {
    __shared__ int sdata[256];
    int b = blockIdx.x, t = threadIdx.x;
    int base = b * C;
    int end = base + C; if (end > N) end = N;
    int running = 0;
    for (int ts = base; ts < end; ts += 256) {
        int idx = ts + t;
        int val = (idx < end) ? cnt[idx] : 0;
        sdata[t] = val;
        __syncthreads();
        for (int s = 1; s < 256; s <<= 1) {
            int v = (t >= s) ? sdata[t - s] : 0;
            __syncthreads();
            sdata[t] += v;
            __syncthreads();
        }
        if (idx < end) row_ptr[idx] = running + sdata[t] - val;
        running += sdata[255];
        __syncthreads();
    }
    if (t == 0) partial[b] = running;
}

__global__ void k_scan_off(int* __restrict__ partial) {
    __shared__ int sdata[256];
    int t = threadIdx.x;
    int val = partial[t];
    sdata[t] = val;
    __syncthreads();
    for (int s = 1; s < 256; s <<= 1) {
        int v = (t >= s) ? sdata[t - s] : 0;
        __syncthreads();
        sdata[t] += v;
        __syncthreads();
    }
    partial[t] = sdata[t] - val;
}

__global__ void k_scan_add(int* __restrict__ row_ptr, int* __restrict__ cursor,
                           const int* __restrict__ partial, const int* __restrict__ cnt,
                           float* __restrict__ dinv, int N, int C, int E) {
    int i = blockIdx.x * 256 + threadIdx.x;
    if (i < N) {
        int v = row_ptr[i] + partial[i / C];
        row_ptr[i] = v;
        cursor[i]  = v;
        dinv[i] = rsqrtf(1.0f + (float)cnt[i]);
    }
    if (i == N) row_ptr[N] = E;
}

// packed edge record: {src, coef bits}
__global__ void k_fill(const int* __restrict__ src, const int* __restrict__ dst,
                       const float* __restrict__ dinv, int* __restrict__ cursor,
                       int2* __restrict__ ecp, int E) {
    int e = blockIdx.x * blockDim.x + threadIdx.x;
    if (e >= E) return;
    int s = src[e], t = dst[e];
    int slot = atomicAdd(&cursor[t], 1);
    ecp[slot] = make_int2(s, __float_as_int(dinv[s] * dinv[t]));
}

// ---------------------------------------------------------------- cast (+ zero layer-0 BN stats)
__global__ void k_cast(const float* __restrict__ in, f16* __restrict__ o, int n4,
                       float* __restrict__ sums, float* __restrict__ sumsq) {
    int i = blockIdx.x * 256 + threadIdx.x;
    if (blockIdx.x == 0) {
        sums[threadIdx.x]  = 0.f;
        sumsq[threadIdx.x] = 0.f;
    }
    if (i >= n4) return;
    float4 v = ((const float4*)in)[i];
    f16x4 h = {(f16)v.x, (f16)v.y, (f16)v.z, (f16)v.w};
    ((f16x4*)o)[i] = h;
}

// ---------------------------------------------------------------- all-layer weight prep (one dispatch)
__global__ void k_prep_w_all(const float* __restrict__ W0, const float* __restrict__ W1,
                             const float* __restrict__ W2, const float* __restrict__ W3,
                             f16* __restrict__ T0, f16* __restrict__ T1,
                             f16* __restrict__ T2, f16* __restrict__ T3) {
    int idx = blockIdx.x * 256 + threadIdx.x;
    if (idx < 16384) {                       // L0: 64x256
        int k = idx >> 8, d = idx & 255;
        T0[(size_t)d * 64 + k] = (f16)W0[idx];
        return;
    }
    idx -= 16384;
    const float* W; f16* T;
    if (idx < 65536)      { W = W1; T = T1; }
    else if (idx < 131072){ W = W2; T = T2; idx -= 65536; }
    else                  { W = W3; T = T3; idx -= 131072; }
    int k = idx >> 8, d = idx & 255;
    T[(size_t)d * 256 + k] = (f16)W[idx];
}

// ---------------------------------------------------------------- MFMA GEMM (128x128, 2x2 waves, 4x4 MFMA)
// OPERAND-SWAPPED: acc[i][j] = mfma(bf[j], af[i], ...) so the C-fragment holds,
// per lane, row = tile_row + (lane&15) and 4 CONSECUTIVE cols quad*4+{0..3}
// -> epilogue stores 16x f16x4 (8B) instead of 64x 2B.
// Staging is register-prefetch pipelined: next K-step's global loads issue
// before the MFMA phase so they are in flight across the barrier.
#define KSTEP 32
#define ATS 40
__global__ __launch_bounds__(256)
void k_gemm(const f16* __restrict__ A, const f16* __restrict__ Wt,
            f16* __restrict__ outh, int N, int K,
            float* __restrict__ sums, float* __restrict__ sumsq,
            float* __restrict__ zs, float* __restrict__ zq) {
    __shared__ __align__(16) f16 As[128 * ATS];
    __shared__ __align__(16) f16 Bs[128 * ATS];
    const int r0 = blockIdx.x * 128;
    const int c0 = blockIdx.y * 128;
    const int t = threadIdx.x;
    const int lane = t & 63, wave = t >> 6;
    const int wr = wave >> 1, wc = wave & 1;
    const int quad = lane >> 4, m = lane & 15;

    if (zs) { zs[t] = 0.f; zq[t] = 0.f; }   // benign multi-block race, all write 0

    f32x4v acc[4][4];
#pragma unroll
    for (int i = 0; i < 4; ++i)
#pragma unroll
        for (int j = 0; j < 4; ++j) acc[i][j] = {0.f, 0.f, 0.f, 0.f};

    const int sr = t >> 1;
    const int sc8 = (t & 1) * 16;
    const int gr = r0 + sr;
    const f16* aprow = A + (size_t)gr * K + sc8;
    const f16* bprow = Wt + (size_t)(c0 + sr) * K + sc8;

    // prime: load K-step 0 into regs
    uint4 a0 = make_uint4(0u,0u,0u,0u), a1 = a0;
    if (gr < N) { a0 = *(const uint4*)aprow; a1 = *(const uint4*)(aprow + 8); }
    uint4 b0 = *(const uint4*)bprow;
    uint4 b1 = *(const uint4*)(bprow + 8);

    for (int k0 = 0; k0 < K; k0 += KSTEP) {
        *(uint4*)(As + sr * ATS + sc8)     = a0;
        *(uint4*)(As + sr * ATS + sc8 + 8) = a1;
        *(uint4*)(Bs + sr * ATS + sc8)     = b0;
        *(uint4*)(Bs + sr * ATS + sc8 + 8) = b1;
        __syncthreads();

        // prefetch next K-step (in flight during ds_read + MFMA)
        if (k0 + KSTEP < K) {
            a0 = make_uint4(0u,0u,0u,0u); a1 = a0;
            if (gr < N) {
                a0 = *(const uint4*)(aprow + k0 + KSTEP);
                a1 = *(const uint4*)(aprow + k0 + KSTEP + 8);
            }
            b0 = *(const uint4*)(bprow + k0 + KSTEP);
            b1 = *(const uint4*)(bprow + k0 + KSTEP + 8);
        }

        f16x8 af[4], bf[4];
#pragma unroll
        for (int i = 0; i < 4; ++i)
            af[i] = *(const f16x8*)(As + (wr * 64 + i * 16 + m) * ATS + quad * 8);
#pragma unroll
        for (int j = 0; j < 4; ++j)
            bf[j] = *(const f16x8*)(Bs + (wc * 64 + j * 16 + m) * ATS + quad * 8);
#pragma unroll
        for (int i = 0; i < 4; ++i)
#pragma unroll
            for (int j = 0; j < 4; ++j)
                acc[i][j] = __builtin_amdgcn_mfma_f32_16x16x32_f16(bf[j], af[i], acc[i][j], 0, 0, 0);
        __syncthreads();
    }

    // epilogue: row = r0 + wr*64 + i*16 + m ; cols c0 + wc*64 + j*16 + quad*4 + {0..3}
#pragma unroll
    for (int i = 0; i < 4; ++i) {
        int row = r0 + wr * 64 + i * 16 + m;
        if (row < N) {
#pragma unroll
            for (int j = 0; j < 4; ++j) {
                f16x4 v = {(f16)acc[i][j][0], (f16)acc[i][j][1],
                           (f16)acc[i][j][2], (f16)acc[i][j][3]};
                *(f16x4*)(outh + (size_t)row * D + c0 + wc * 64 + j * 16 + quad * 4) = v;
            }
        }
    }

    if (sums) {
        __shared__ float cs[128], css[128];
        if (t < 128) { cs[t] = 0.f; css[t] = 0.f; }
        __syncthreads();
#pragma unroll
        for (int j = 0; j < 4; ++j) {
#pragma unroll
            for (int r = 0; r < 4; ++r) {
                int f = wc * 64 + j * 16 + quad * 4 + r;
                float s = 0.f, q = 0.f;
#pragma unroll
                for (int i = 0; i < 4; ++i) {
                    float v = acc[i][j][r];
                    s += v; q += v * v;
                }
                atomicAdd(&cs[f], s);
                atomicAdd(&css[f], q);
            }
        }
        __syncthreads();
        if (t < 128) {
            atomicAdd(&sums[c0 + t], cs[t]);
            atomicAdd(&sumsq[c0 + t], css[t]);
        }
    }
}

// ---------------------------------------------------------------- gather, 256-dim rows (layers 1-3)
// wave-per-node, f16x4/lane, predicated x8 unroll, packed int2 edges (round-13 proven body).
__global__ __launch_bounds__(256)
void k_gather(const int* __restrict__ row_ptr, const int2* __restrict__ ecp,
              const f16* __restrict__ hw, const float* __restrict__ dinv,
              f16* __restrict__ out, float* __restrict__ sums,
              float* __restrict__ sumsq, int N) {
    const int lane = threadIdx.x & 63;
    const int wave = threadIdx.x >> 6;
    const f16x4* __restrict__ hw4 = (const f16x4*)hw;
    f16x4* __restrict__ out4 = (f16x4*)out;

    float4 s4  = make_float4(0.f, 0.f, 0.f, 0.f);
    float4 ss4 = make_float4(0.f, 0.f, 0.f, 0.f);

    int wslot  = blockIdx.x * 4 + wave;
    int wtotal = gridDim.x * 4;
    for (int i = wslot; i < N; i += wtotal) {
        int lo = row_ptr[i];
        int hi = row_ptr[i + 1];
        float dd = dinv[i]; dd *= dd;
        f16x4 hv = hw4[(size_t)i * 64 + lane];
        float4 acc;
        acc.x = (float)hv[0] * dd;
        acc.y = (float)hv[1] * dd;
        acc.z = (float)hv[2] * dd;
        acc.w = (float)hv[3] * dd;

        for (int e = lo; e < hi; e += 8) {
            int nd[8]; float cf[8];
#pragma unroll
            for (int j = 0; j < 8; ++j) {
                int ej = e + j;
                int2 ec = ecp[(ej < hi) ? ej : lo];
                nd[j] = ec.x;
                cf[j] = (ej < hi) ? __int_as_float(ec.y) : 0.f;
            }
            f16x4 r[8];
#pragma unroll
            for (int j = 0; j < 8; ++j) r[j] = hw4[(size_t)nd[j] * 64 + lane];
#pragma unroll
            for (int j = 0; j < 8; ++j) {
                acc.x = fmaf((float)r[j][0], cf[j], acc.x);
                acc.y = fmaf((float)r[j][1], cf[j], acc.y);
                acc.z = fmaf((float)r[j][2], cf[j], acc.z);
                acc.w = fmaf((float)r[j][3], cf[j], acc.w);
            }
        }

        f16x4 o = {(f16)acc.x, (f16)acc.y, (f16)acc.z, (f16)acc.w};
        out4[(size_t)i * 64 + lane] = o;
        s4.x += acc.x; s4.y += acc.y; s4.z += acc.z; s4.w += acc.w;
        ss4.x += acc.x * acc.x; ss4.y += acc.y * acc.y;
        ss4.z += acc.z * acc.z; ss4.w += acc.w * acc.w;
    }

    __shared__ float rs[4][256];
    __shared__ float rss[4][256];
    int f = lane * 4;
    rs[wave][f + 0] = s4.x;  rs[wave][f + 1] = s4.y;
    rs[wave][f + 2] = s4.z;  rs[wave][f + 3] = s4.w;
    rss[wave][f + 0] = ss4.x; rss[wave][f + 1] = ss4.y;
    rss[wave][f + 2] = ss4.z; rss[wave][f + 3] = ss4.w;
    __syncthreads();
    int t = threadIdx.x;
    float rsum  = rs[0][t] + rs[1][t] + rs[2][t] + rs[3][t];
    float rsum2 = rss[0][t] + rss[1][t] + rss[2][t] + rss[3][t];
    atomicAdd(&sums[t], rsum);
    atomicAdd(&sumsq[t], rsum2);
}

// ---------------------------------------------------------------- gather64: quad-node per wave (layer 0 on X)
__global__ __launch_bounds__(256)
void k_gather64(const int* __restrict__ row_ptr, const int2* __restrict__ ecp,
                const f16* __restrict__ xh, const float* __restrict__ dinv,
                f16* __restrict__ aggx, int N) {
    const int lane = threadIdx.x & 63;
    const int wave = threadIdx.x >> 6;
    const int q = lane >> 4, m = lane & 15;
    const f16x4* __restrict__ x4 = (const f16x4*)xh;
    f16x4* __restrict__ o4 = (f16x4*)aggx;

    int slot   = blockIdx.x * 4 + wave;
    int stride = gridDim.x * 4;
    for (int i0 = slot * 4; i0 < N; i0 += stride * 4) {
        int i = i0 + q;
        bool act = i < N;
        int lo = act ? row_ptr[i] : 0;
        int hi = act ? row_ptr[i + 1] : 0;
        float dd = act ? dinv[i] : 0.f; dd *= dd;
        f16x4 hv = act ? x4[(size_t)i * 16 + m] : (f16x4){0,0,0,0};
        float4 acc;
        acc.x = (float)hv[0]*dd; acc.y = (float)hv[1]*dd;
        acc.z = (float)hv[2]*dd; acc.w = (float)hv[3]*dd;

        for (int e = lo; e < hi; e += 8) {
            int nd[8]; float cf[8];
#pragma unroll
            for (int j = 0; j < 8; ++j) {
                int ej = e + j;
                int2 ec = ecp[(ej < hi) ? ej : lo];
                nd[j] = ec.x;
                cf[j] = (ej < hi) ? __int_as_float(ec.y) : 0.f;
            }
            f16x4 r[8];
#pragma unroll
            for (int j = 0; j < 8; ++j) r[j] = x4[(size_t)nd[j] * 16 + m];
#pragma unroll
            for (int j = 0; j < 8; ++j) {
                acc.x = fmaf((float)r[j][0], cf[j], acc.x);
                acc.y = fmaf((float)r[j][1], cf[j], acc.y);
                acc.z = fmaf((float)r[j][2], cf[j], acc.z);
                acc.w = fmaf((float)r[j][3], cf[j], acc.w);
            }
        }
        if (act) {
            f16x4 o = {(f16)acc.x, (f16)acc.y, (f16)acc.z, (f16)acc.w};
            o4[(size_t)i * 16 + m] = o;
        }
    }
}

// ---------------------------------------------------------------- BN + tanh (f16 in, f16 out)
__global__ void k_bn_tanh_h(const f16* __restrict__ h, const float* __restrict__ sums,
                            const float* __restrict__ sumsq, const float* __restrict__ g,
                            const float* __restrict__ be, float Ninv,
                            f16* __restrict__ hh, int n4) {
    int i = blockIdx.x * blockDim.x + threadIdx.x;
    if (i >= n4) return;
    int d = (i & 63) * 4;
    f16x4 v = ((const f16x4*)h)[i];
    f16x4 o;
#pragma unroll
    for (int j = 0; j < 4; ++j) {
        float mu  = sums[d + j] * Ninv;
        float var = sumsq[d + j] * Ninv - mu * mu;
        float s   = g[d + j] * rsqrtf(var + EPS);
        float sh  = be[d + j] - mu * s;
        o[j] = (f16)tanhf(fmaf((float)v[j], s, sh));
    }
    ((f16x4*)hh)[i] = o;
}

// ---------------------------------------------------------------- pool with fused last-layer BN + tanh
__device__ __forceinline__ int lb(const int* __restrict__ a, int n, int v) {
    int lo = 0, hi = n;
    while (lo < hi) {
        int mid = (lo + hi) >> 1;
        if (a[mid] < v) lo = mid + 1; else hi = mid;
    }
    return lo;
}

__global__ void k_pool(const f16* __restrict__ agg, const float* __restrict__ sums,
                       const float* __restrict__ sumsq, const float* __restrict__ gg,
                       const float* __restrict__ be, float Ninv,
                       const int* __restrict__ batch,
                       const float* __restrict__ Wout, const float* __restrict__ bout,
                       float* __restrict__ out, float* __restrict__ hidden, int N) {
    int g = blockIdx.x;
    int d = threadIdx.x;
    float mu  = sums[d] * Ninv;
    float var = sumsq[d] * Ninv - mu * mu;
    float sc  = gg[d] * rsqrtf(var + EPS);
    float sh  = be[d] - mu * sc;

    int lo = lb(batch, N, g);
    int hi = lb(batch, N, g + 1);
    float mx = -INFINITY, sm = 0.0f;
    for (int i = lo; i < hi; ++i) {
        float v = tanhf(fmaf((float)agg[(size_t)i * D + d], sc, sh));
        mx = fmaxf(mx, v);
        sm += v;
    }
    float mean = sm / (float)(hi - lo);
    hidden[(size_t)g * (2 * D) + d] = mx;
    hidden[(size_t)g * (2 * D) + D + d] = mean;

    float p = mx * Wout[d] + mean * Wout[D + d];
    __shared__ float red[256];
    red[d] = p;
    __syncthreads();
    for (int s = 128; s > 0; s >>= 1) {
        if (d < s) red[d] += red[d + s];
        __syncthreads();
    }
    if (d == 0) out[g] = red[0] + bout[0];
}

// ----------------------------------------------------------------
extern "C" void kernel_launch(void* const* d_in, const int* in_sizes, int n_in,
                              void* d_out, int out_size, void* d_ws, size_t ws_size,
                              hipStream_t stream) {
    const float* x          = (const float*)d_in[0];
    const int*   edge_index = (const int*)d_in[1];
    const int*   batch      = (const int*)d_in[2];
    const float* Wl[4] = {(const float*)d_in[4], (const float*)d_in[6],
                          (const float*)d_in[8], (const float*)d_in[10]};
    const float* gl[4]  = {(const float*)d_in[12], (const float*)d_in[14],
                           (const float*)d_in[16], (const float*)d_in[18]};
    const float* bel[4] = {(const float*)d_in[13], (const float*)d_in[15],
                           (const float*)d_in[17], (const float*)d_in[19]};
    const float* Wout = (const float*)d_in[20];
    const float* bout = (const float*)d_in[21];

    const int N = in_sizes[0] / 64;       // 50000
    const int E = in_sizes[1] / 2;        // 800000
    const int B = out_size / (1 + 2 * D); // 1000

    const int* srcv = edge_index;
    const int* dstv = edge_index + E;

    // workspace carve-up
    f16*   hw_h    = (f16*)d_ws;                // [N,D] GEMM out
    f16*   hh      = hw_h + (size_t)N * D;      // [N,D] activations
    f16*   agg_h   = hh + (size_t)N * D;        // [N,D] gather out
    f16*   xh      = agg_h + (size_t)N * D;     // [N,64]
    f16*   aggx    = xh + (size_t)N * 64;       // [N,64]
    f16*   Wt0     = aggx + (size_t)N * 64;     // [256,64]
    f16*   Wt1     = Wt0 + 256 * 64;            // [256,256] x3
    f16*   Wt2     = Wt1 + 256 * 256;
    f16*   Wt3     = Wt2 + 256 * 256;
    float* dinv    = (float*)(Wt3 + 256 * 256); // [N]
    float* sums    = dinv + N;                  // [D]
    float* sumsq   = sums + D;                  // [D]
    int2*  ecp     = (int2*)(sumsq + D);        // [E]
    int*   cnt     = (int*)(ecp + E);           // [N]
    int*   row_ptr = cnt + N;                   // [N+1]
    int*   cursor  = row_ptr + N + 1;           // [N]
    int*   partial = cursor + N;                // [SCAN_NB]

    float* out_p    = (float*)d_out;            // [B]
    float* hidden_p = out_p + B;                // [B, 512]

    // ---- CSR build
    hipMemsetAsync(cnt, 0, (size_t)N * sizeof(int), stream);
    k_count<<<(E + 255) / 256, 256, 0, stream>>>(dstv, cnt, E);
    const int C = (N + SCAN_NB - 1) / SCAN_NB;
    k_scan_part<<<SCAN_NB, 256, 0, stream>>>(cnt, row_ptr, partial, N, C);
    k_scan_off<<<1, 256, 0, stream>>>(partial);
    k_scan_add<<<(N + 1 + 255) / 256, 256, 0, stream>>>(row_ptr, cursor, partial,
                                                        cnt, dinv, N, C, E);
    k_fill<<<(E + 255) / 256, 256, 0, stream>>>(srcv, dstv, dinv, cursor, ecp, E);

    // x -> f16 (+ zero layer-0 stats); all weights in one dispatch
    k_cast<<<(N * 64 / 4 + 255) / 256, 256, 0, stream>>>(x, xh, N * 64 / 4, sums, sumsq);
    k_prep_w_all<<<(16384 + 3 * 65536 + 255) / 256, 256, 0, stream>>>(
        Wl[0], Wl[1], Wl[2], Wl[3], Wt0, Wt1, Wt2, Wt3);

    const dim3 gemm_grid((N + 127) / 128, 2);
    const int nd4 = N * D / 4;
    const float Ninv = 1.0f / (float)N;
    f16* Wts[4] = {Wt0, Wt1, Wt2, Wt3};

    // ---- layer 0: quad-gather agg(X) -> GEMM(+stats) -> BN+tanh
    k_gather64<<<2048, 256, 0, stream>>>(row_ptr, ecp, xh, dinv, aggx, N);
    k_gemm<<<gemm_grid, 256, 0, stream>>>(aggx, Wt0, hw_h, N, 64,
                                          sums, sumsq, nullptr, nullptr);
    k_bn_tanh_h<<<(nd4 + 255) / 256, 256, 0, stream>>>(
        hw_h, sums, sumsq, gl[0], bel[0], Ninv, hh, nd4);

    // ---- layers 1-3: GEMM(zeroes stats) -> gather(+stats) -> BN+tanh (layer 3 BN fused into pool)
    for (int l = 1; l < 4; ++l) {
        k_gemm<<<gemm_grid, 256, 0, stream>>>(hh, Wts[l], hw_h, N, 256,
                                              nullptr, nullptr, sums, sumsq);
        k_gather<<<2048, 256, 0, stream>>>(row_ptr, ecp, hw_h, dinv,
                                           agg_h, sums, sumsq, N);
        if (l < 3) {
            k_bn_tanh_h<<<(nd4 + 255) / 256, 256, 0, stream>>>(
                agg_h, sums, sumsq, gl[l], bel[l], Ninv, hh, nd4);
        }
    }

    k_pool<<<B, 256, 0, stream>>>(agg_h, sums, sumsq, gl[3], bel[3], Ninv,
                                  batch, Wout, bout, out_p, hidden_p, N);
}

// Round 15
// 748.702 us; speedup vs baseline: 1.0679x; 1.0679x over previous
//
#include <hip/hip_runtime.h>
#include <hip/hip_bf16.h>
#include <math.h>

#define D 256
#define EPS 1e-5f
#define SCAN_NB 256

typedef _Float16 f16;
typedef _Float16 f16x2 __attribute__((ext_vector_type(2)));
typedef _Float16 f16x4 __attribute__((ext_vector_type(4)));
typedef _Float16 f16x8 __attribute__((ext_vector_type(8)));
typedef float f32x4v __attribute__((ext_vector_type(4)));

// ---------------------------------------------------------------- CSR build
__global__ void k_count(const int* __restrict__ dst, int* __restrict__ cnt, int E) {
    int e = blockIdx.x * blockDim.x + threadIdx.x;
    if (e < E) atomicAdd(&cnt[dst[e]], 1);
}

__global__ void k_scan_part(const int* __restrict__ cnt, int* __restrict__ row_ptr,
                            int* __restrict__ partial, int N, int C) {
    __shared__ int sdata[256];
    int b = blockIdx.x, t = threadIdx.x;
    int base = b * C;
    int end = base + C; if (end > N) end = N;
    int running = 0;
    for (int ts = base; ts < end; ts += 256) {
        int idx = ts + t;
        int val = (idx < end) ? cnt[idx] : 0;
        sdata[t] = val;
        __syncthreads();
        for (int s = 1; s < 256; s <<= 1) {
            int v = (t >= s) ? sdata[t - s] : 0;
            __syncthreads();
            sdata[t] += v;
            __syncthreads();
        }
        if (idx < end) row_ptr[idx] = running + sdata[t] - val;
        running += sdata[255];
        __syncthreads();
    }
    if (t == 0) partial[b] = running;
}

__global__ void k_scan_off(int* __restrict__ partial) {
    __shared__ int sdata[256];
    int t = threadIdx.x;
    int val = partial[t];
    sdata[t] = val;
    __syncthreads();
    for (int s = 1; s < 256; s <<= 1) {
        int v = (t >= s) ? sdata[t - s] : 0;
        __syncthreads();
        sdata[t] += v;
        __syncthreads();
    }
    partial[t] = sdata[t] - val;
}

__global__ void k_scan_add(int* __restrict__ row_ptr, int* __restrict__ cursor,
                           const int* __restrict__ partial, const int* __restrict__ cnt,
                           float* __restrict__ dinv, int N, int C, int E) {
    int i = blockIdx.x * 256 + threadIdx.x;
    if (i < N) {
        int v = row_ptr[i] + partial[i / C];
        row_ptr[i] = v;
        cursor[i]  = v;
        dinv[i] = rsqrtf(1.0f + (float)cnt[i]);
    }
    if (i == N) row_ptr[N] = E;
}

// packed edge record: {src, coef bits}
__global__ void k_fill(const int* __restrict__ src, const int* __restrict__ dst,
                       const float* __restrict__ dinv, int* __restrict__ cursor,
                       int2* __restrict__ ecp, int E) {
    int e = blockIdx.x * blockDim.x + threadIdx.x;
    if (e >= E) return;
    int s = src[e], t = dst[e];
    int slot = atomicAdd(&cursor[t], 1);
    ecp[slot] = make_int2(s, __float_as_int(dinv[s] * dinv[t]));
}

// ---------------------------------------------------------------- cast (+ zero layer-0 BN stats)
__global__ void k_cast(const float* __restrict__ in, f16* __restrict__ o, int n4,
                       float* __restrict__ sums, float* __restrict__ sumsq) {
    int i = blockIdx.x * 256 + threadIdx.x;
    if (blockIdx.x == 0) {
        sums[threadIdx.x]  = 0.f;
        sumsq[threadIdx.x] = 0.f;
    }
    if (i >= n4) return;
    float4 v = ((const float4*)in)[i];
    f16x4 h = {(f16)v.x, (f16)v.y, (f16)v.z, (f16)v.w};
    ((f16x4*)o)[i] = h;
}

// ---------------------------------------------------------------- all-layer weight prep (one dispatch)
__global__ void k_prep_w_all(const float* __restrict__ W0, const float* __restrict__ W1,
                             const float* __restrict__ W2, const float* __restrict__ W3,
                             f16* __restrict__ T0, f16* __restrict__ T1,
                             f16* __restrict__ T2, f16* __restrict__ T3) {
    int idx = blockIdx.x * 256 + threadIdx.x;
    if (idx < 16384) {                       // L0: 64x256
        int k = idx >> 8, d = idx & 255;
        T0[(size_t)d * 64 + k] = (f16)W0[idx];
        return;
    }
    idx -= 16384;
    const float* W; f16* T;
    if (idx < 65536)      { W = W1; T = T1; }
    else if (idx < 131072){ W = W2; T = T2; idx -= 65536; }
    else                  { W = W3; T = T3; idx -= 131072; }
    int k = idx >> 8, d = idx & 255;
    T[(size_t)d * 256 + k] = (f16)W[idx];
}

// ---------------------------------------------------------------- MFMA GEMM (128x128, 2x2 waves, 4x4 MFMA)
// Round-13 proven version: natural operand order (4x32B store segments/instr),
// no register prefetch.
#define KSTEP 32
#define ATS 40
__global__ __launch_bounds__(256)
void k_gemm(const f16* __restrict__ A, const f16* __restrict__ Wt,
            f16* __restrict__ outh, int N, int K,
            float* __restrict__ sums, float* __restrict__ sumsq,
            float* __restrict__ zs, float* __restrict__ zq) {
    __shared__ __align__(16) f16 As[128 * ATS];
    __shared__ __align__(16) f16 Bs[128 * ATS];
    const int r0 = blockIdx.x * 128;
    const int c0 = blockIdx.y * 128;
    const int t = threadIdx.x;
    const int lane = t & 63, wave = t >> 6;
    const int wr = wave >> 1, wc = wave & 1;
    const int quad = lane >> 4, m = lane & 15;

    if (zs) { zs[t] = 0.f; zq[t] = 0.f; }   // benign multi-block race, all write 0

    f32x4v acc[4][4];
#pragma unroll
    for (int i = 0; i < 4; ++i)
#pragma unroll
        for (int j = 0; j < 4; ++j) acc[i][j] = {0.f, 0.f, 0.f, 0.f};

    const int sr = t >> 1;
    const int sc8 = (t & 1) * 16;

    for (int k0 = 0; k0 < K; k0 += KSTEP) {
        int gr = r0 + sr;
        uint4 a0 = make_uint4(0u,0u,0u,0u), a1 = make_uint4(0u,0u,0u,0u);
        if (gr < N) {
            const f16* ap = A + (size_t)gr * K + k0 + sc8;
            a0 = *(const uint4*)ap;
            a1 = *(const uint4*)(ap + 8);
        }
        *(uint4*)(As + sr * ATS + sc8)     = a0;
        *(uint4*)(As + sr * ATS + sc8 + 8) = a1;
        const f16* bp = Wt + (size_t)(c0 + sr) * K + k0 + sc8;
        *(uint4*)(Bs + sr * ATS + sc8)     = *(const uint4*)bp;
        *(uint4*)(Bs + sr * ATS + sc8 + 8) = *(const uint4*)(bp + 8);
        __syncthreads();

        f16x8 af[4], bf[4];
#pragma unroll
        for (int i = 0; i < 4; ++i)
            af[i] = *(const f16x8*)(As + (wr * 64 + i * 16 + m) * ATS + quad * 8);
#pragma unroll
        for (int j = 0; j < 4; ++j)
            bf[j] = *(const f16x8*)(Bs + (wc * 64 + j * 16 + m) * ATS + quad * 8);
#pragma unroll
        for (int i = 0; i < 4; ++i)
#pragma unroll
            for (int j = 0; j < 4; ++j)
                acc[i][j] = __builtin_amdgcn_mfma_f32_16x16x32_f16(af[i], bf[j], acc[i][j], 0, 0, 0);
        __syncthreads();
    }

#pragma unroll
    for (int i = 0; i < 4; ++i) {
#pragma unroll
        for (int r = 0; r < 4; ++r) {
            int row = r0 + wr * 64 + i * 16 + quad * 4 + r;
            if (row < N) {
#pragma unroll
                for (int j = 0; j < 4; ++j) {
                    int colm = c0 + wc * 64 + j * 16 + m;
                    outh[(size_t)row * D + colm] = (f16)acc[i][j][r];
                }
            }
        }
    }

    if (sums) {
        __shared__ float cs[128], css[128];
        if (t < 128) { cs[t] = 0.f; css[t] = 0.f; }
        __syncthreads();
#pragma unroll
        for (int j = 0; j < 4; ++j) {
            int f = wc * 64 + j * 16 + m;
            float s = 0.f, q = 0.f;
#pragma unroll
            for (int i = 0; i < 4; ++i)
#pragma unroll
                for (int r = 0; r < 4; ++r) {
                    float v = acc[i][j][r];
                    s += v; q += v * v;
                }
            atomicAdd(&cs[f], s);
            atomicAdd(&css[f], q);
        }
        __syncthreads();
        if (t < 128) {
            atomicAdd(&sums[c0 + t], cs[t]);
            atomicAdd(&sumsq[c0 + t], css[t]);
        }
    }
}

// ---------------------------------------------------------------- gather, 256-dim rows (layers 1-3)
// wave-per-node, f16x4/lane, predicated x8 unroll, packed int2 edges (round-13 proven body).
__global__ __launch_bounds__(256)
void k_gather(const int* __restrict__ row_ptr, const int2* __restrict__ ecp,
              const f16* __restrict__ hw, const float* __restrict__ dinv,
              f16* __restrict__ out, float* __restrict__ sums,
              float* __restrict__ sumsq, int N) {
    const int lane = threadIdx.x & 63;
    const int wave = threadIdx.x >> 6;
    const f16x4* __restrict__ hw4 = (const f16x4*)hw;
    f16x4* __restrict__ out4 = (f16x4*)out;

    float4 s4  = make_float4(0.f, 0.f, 0.f, 0.f);
    float4 ss4 = make_float4(0.f, 0.f, 0.f, 0.f);

    int wslot  = blockIdx.x * 4 + wave;
    int wtotal = gridDim.x * 4;
    for (int i = wslot; i < N; i += wtotal) {
        int lo = row_ptr[i];
        int hi = row_ptr[i + 1];
        float dd = dinv[i]; dd *= dd;
        f16x4 hv = hw4[(size_t)i * 64 + lane];
        float4 acc;
        acc.x = (float)hv[0] * dd;
        acc.y = (float)hv[1] * dd;
        acc.z = (float)hv[2] * dd;
        acc.w = (float)hv[3] * dd;

        for (int e = lo; e < hi; e += 8) {
            int nd[8]; float cf[8];
#pragma unroll
            for (int j = 0; j < 8; ++j) {
                int ej = e + j;
                int2 ec = ecp[(ej < hi) ? ej : lo];
                nd[j] = ec.x;
                cf[j] = (ej < hi) ? __int_as_float(ec.y) : 0.f;
            }
            f16x4 r[8];
#pragma unroll
            for (int j = 0; j < 8; ++j) r[j] = hw4[(size_t)nd[j] * 64 + lane];
#pragma unroll
            for (int j = 0; j < 8; ++j) {
                acc.x = fmaf((float)r[j][0], cf[j], acc.x);
                acc.y = fmaf((float)r[j][1], cf[j], acc.y);
                acc.z = fmaf((float)r[j][2], cf[j], acc.z);
                acc.w = fmaf((float)r[j][3], cf[j], acc.w);
            }
        }

        f16x4 o = {(f16)acc.x, (f16)acc.y, (f16)acc.z, (f16)acc.w};
        out4[(size_t)i * 64 + lane] = o;
        s4.x += acc.x; s4.y += acc.y; s4.z += acc.z; s4.w += acc.w;
        ss4.x += acc.x * acc.x; ss4.y += acc.y * acc.y;
        ss4.z += acc.z * acc.z; ss4.w += acc.w * acc.w;
    }

    __shared__ float rs[4][256];
    __shared__ float rss[4][256];
    int f = lane * 4;
    rs[wave][f + 0] = s4.x;  rs[wave][f + 1] = s4.y;
    rs[wave][f + 2] = s4.z;  rs[wave][f + 3] = s4.w;
    rss[wave][f + 0] = ss4.x; rss[wave][f + 1] = ss4.y;
    rss[wave][f + 2] = ss4.z; rss[wave][f + 3] = ss4.w;
    __syncthreads();
    int t = threadIdx.x;
    float rsum  = rs[0][t] + rs[1][t] + rs[2][t] + rs[3][t];
    float rsum2 = rss[0][t] + rss[1][t] + rss[2][t] + rss[3][t];
    atomicAdd(&sums[t], rsum);
    atomicAdd(&sumsq[t], rsum2);
}

// ---------------------------------------------------------------- gather64: quad-node per wave (layer 0 on X)
__global__ __launch_bounds__(256)
void k_gather64(const int* __restrict__ row_ptr, const int2* __restrict__ ecp,
                const f16* __restrict__ xh, const float* __restrict__ dinv,
                f16* __restrict__ aggx, int N) {
    const int lane = threadIdx.x & 63;
    const int wave = threadIdx.x >> 6;
    const int q = lane >> 4, m = lane & 15;
    const f16x4* __restrict__ x4 = (const f16x4*)xh;
    f16x4* __restrict__ o4 = (f16x4*)aggx;

    int slot   = blockIdx.x * 4 + wave;
    int stride = gridDim.x * 4;
    for (int i0 = slot * 4; i0 < N; i0 += stride * 4) {
        int i = i0 + q;
        bool act = i < N;
        int lo = act ? row_ptr[i] : 0;
        int hi = act ? row_ptr[i + 1] : 0;
        float dd = act ? dinv[i] : 0.f; dd *= dd;
        f16x4 hv = act ? x4[(size_t)i * 16 + m] : (f16x4){0,0,0,0};
        float4 acc;
        acc.x = (float)hv[0]*dd; acc.y = (float)hv[1]*dd;
        acc.z = (float)hv[2]*dd; acc.w = (float)hv[3]*dd;

        for (int e = lo; e < hi; e += 8) {
            int nd[8]; float cf[8];
#pragma unroll
            for (int j = 0; j < 8; ++j) {
                int ej = e + j;
                int2 ec = ecp[(ej < hi) ? ej : lo];
                nd[j] = ec.x;
                cf[j] = (ej < hi) ? __int_as_float(ec.y) : 0.f;
            }
            f16x4 r[8];
#pragma unroll
            for (int j = 0; j < 8; ++j) r[j] = x4[(size_t)nd[j] * 16 + m];
#pragma unroll
            for (int j = 0; j < 8; ++j) {
                acc.x = fmaf((float)r[j][0], cf[j], acc.x);
                acc.y = fmaf((float)r[j][1], cf[j], acc.y);
                acc.z = fmaf((float)r[j][2], cf[j], acc.z);
                acc.w = fmaf((float)r[j][3], cf[j], acc.w);
            }
        }
        if (act) {
            f16x4 o = {(f16)acc.x, (f16)acc.y, (f16)acc.z, (f16)acc.w};
            o4[(size_t)i * 16 + m] = o;
        }
    }
}

// ---------------------------------------------------------------- BN + tanh (f16 in, f16 out)
__global__ void k_bn_tanh_h(const f16* __restrict__ h, const float* __restrict__ sums,
                            const float* __restrict__ sumsq, const float* __restrict__ g,
                            const float* __restrict__ be, float Ninv,
                            f16* __restrict__ hh, int n4) {
    int i = blockIdx.x * blockDim.x + threadIdx.x;
    if (i >= n4) return;
    int d = (i & 63) * 4;
    f16x4 v = ((const f16x4*)h)[i];
    f16x4 o;
#pragma unroll
    for (int j = 0; j < 4; ++j) {
        float mu  = sums[d + j] * Ninv;
        float var = sumsq[d + j] * Ninv - mu * mu;
        float s   = g[d + j] * rsqrtf(var + EPS);
        float sh  = be[d + j] - mu * s;
        o[j] = (f16)tanhf(fmaf((float)v[j], s, sh));
    }
    ((f16x4*)hh)[i] = o;
}

// ---------------------------------------------------------------- pool with fused last-layer BN + tanh
__device__ __forceinline__ int lb(const int* __restrict__ a, int n, int v) {
    int lo = 0, hi = n;
    while (lo < hi) {
        int mid = (lo + hi) >> 1;
        if (a[mid] < v) lo = mid + 1; else hi = mid;
    }
    return lo;
}

__global__ void k_pool(const f16* __restrict__ agg, const float* __restrict__ sums,
                       const float* __restrict__ sumsq, const float* __restrict__ gg,
                       const float* __restrict__ be, float Ninv,
                       const int* __restrict__ batch,
                       const float* __restrict__ Wout, const float* __restrict__ bout,
                       float* __restrict__ out, float* __restrict__ hidden, int N) {
    int g = blockIdx.x;
    int d = threadIdx.x;
    float mu  = sums[d] * Ninv;
    float var = sumsq[d] * Ninv - mu * mu;
    float sc  = gg[d] * rsqrtf(var + EPS);
    float sh  = be[d] - mu * sc;

    int lo = lb(batch, N, g);
    int hi = lb(batch, N, g + 1);
    float mx = -INFINITY, sm = 0.0f;
    for (int i = lo; i < hi; ++i) {
        float v = tanhf(fmaf((float)agg[(size_t)i * D + d], sc, sh));
        mx = fmaxf(mx, v);
        sm += v;
    }
    float mean = sm / (float)(hi - lo);
    hidden[(size_t)g * (2 * D) + d] = mx;
    hidden[(size_t)g * (2 * D) + D + d] = mean;

    float p = mx * Wout[d] + mean * Wout[D + d];
    __shared__ float red[256];
    red[d] = p;
    __syncthreads();
    for (int s = 128; s > 0; s >>= 1) {
        if (d < s) red[d] += red[d + s];
        __syncthreads();
    }
    if (d == 0) out[g] = red[0] + bout[0];
}

// ----------------------------------------------------------------
extern "C" void kernel_launch(void* const* d_in, const int* in_sizes, int n_in,
                              void* d_out, int out_size, void* d_ws, size_t ws_size,
                              hipStream_t stream) {
    const float* x          = (const float*)d_in[0];
    const int*   edge_index = (const int*)d_in[1];
    const int*   batch      = (const int*)d_in[2];
    const float* Wl[4] = {(const float*)d_in[4], (const float*)d_in[6],
                          (const float*)d_in[8], (const float*)d_in[10]};
    const float* gl[4]  = {(const float*)d_in[12], (const float*)d_in[14],
                           (const float*)d_in[16], (const float*)d_in[18]};
    const float* bel[4] = {(const float*)d_in[13], (const float*)d_in[15],
                           (const float*)d_in[17], (const float*)d_in[19]};
    const float* Wout = (const float*)d_in[20];
    const float* bout = (const float*)d_in[21];

    const int N = in_sizes[0] / 64;       // 50000
    const int E = in_sizes[1] / 2;        // 800000
    const int B = out_size / (1 + 2 * D); // 1000

    const int* srcv = edge_index;
    const int* dstv = edge_index + E;

    // workspace carve-up
    f16*   hw_h    = (f16*)d_ws;                // [N,D] GEMM out
    f16*   hh      = hw_h + (size_t)N * D;      // [N,D] activations
    f16*   agg_h   = hh + (size_t)N * D;        // [N,D] gather out
    f16*   xh      = agg_h + (size_t)N * D;     // [N,64]
    f16*   aggx    = xh + (size_t)N * 64;       // [N,64]
    f16*   Wt0     = aggx + (size_t)N * 64;     // [256,64]
    f16*   Wt1     = Wt0 + 256 * 64;            // [256,256] x3
    f16*   Wt2     = Wt1 + 256 * 256;
    f16*   Wt3     = Wt2 + 256 * 256;
    float* dinv    = (float*)(Wt3 + 256 * 256); // [N]
    float* sums    = dinv + N;                  // [D]
    float* sumsq   = sums + D;                  // [D]
    int2*  ecp     = (int2*)(sumsq + D);        // [E]
    int*   cnt     = (int*)(ecp + E);           // [N]
    int*   row_ptr = cnt + N;                   // [N+1]
    int*   cursor  = row_ptr + N + 1;           // [N]
    int*   partial = cursor + N;                // [SCAN_NB]

    float* out_p    = (float*)d_out;            // [B]
    float* hidden_p = out_p + B;                // [B, 512]

    // ---- CSR build
    hipMemsetAsync(cnt, 0, (size_t)N * sizeof(int), stream);
    k_count<<<(E + 255) / 256, 256, 0, stream>>>(dstv, cnt, E);
    const int C = (N + SCAN_NB - 1) / SCAN_NB;
    k_scan_part<<<SCAN_NB, 256, 0, stream>>>(cnt, row_ptr, partial, N, C);
    k_scan_off<<<1, 256, 0, stream>>>(partial);
    k_scan_add<<<(N + 1 + 255) / 256, 256, 0, stream>>>(row_ptr, cursor, partial,
                                                        cnt, dinv, N, C, E);
    k_fill<<<(E + 255) / 256, 256, 0, stream>>>(srcv, dstv, dinv, cursor, ecp, E);

    // x -> f16 (+ zero layer-0 stats); all weights in one dispatch
    k_cast<<<(N * 64 / 4 + 255) / 256, 256, 0, stream>>>(x, xh, N * 64 / 4, sums, sumsq);
    k_prep_w_all<<<(16384 + 3 * 65536 + 255) / 256, 256, 0, stream>>>(
        Wl[0], Wl[1], Wl[2], Wl[3], Wt0, Wt1, Wt2, Wt3);

    const dim3 gemm_grid((N + 127) / 128, 2);
    const int nd4 = N * D / 4;
    const float Ninv = 1.0f / (float)N;
    f16* Wts[4] = {Wt0, Wt1, Wt2, Wt3};

    // ---- layer 0: quad-gather agg(X) -> GEMM(+stats) -> BN+tanh
    k_gather64<<<2048, 256, 0, stream>>>(row_ptr, ecp, xh, dinv, aggx, N);
    k_gemm<<<gemm_grid, 256, 0, stream>>>(aggx, Wt0, hw_h, N, 64,
                                          sums, sumsq, nullptr, nullptr);
    k_bn_tanh_h<<<(nd4 + 255) / 256, 256, 0, stream>>>(
        hw_h, sums, sumsq, gl[0], bel[0], Ninv, hh, nd4);

    // ---- layers 1-3: GEMM(zeroes stats) -> gather(+stats) -> BN+tanh (layer 3 BN fused into pool)
    for (int l = 1; l < 4; ++l) {
        k_gemm<<<gemm_grid, 256, 0, stream>>>(hh, Wts[l], hw_h, N, 256,
                                              nullptr, nullptr, sums, sumsq);
        k_gather<<<2048, 256, 0, stream>>>(row_ptr, ecp, hw_h, dinv,
                                           agg_h, sums, sumsq, N);
        if (l < 3) {
            k_bn_tanh_h<<<(nd4 + 255) / 256, 256, 0, stream>>>(
                agg_h, sums, sumsq, gl[l], bel[l], Ninv, hh, nd4);
        }
    }

    k_pool<<<B, 256, 0, stream>>>(agg_h, sums, sumsq, gl[3], bel[3], Ninv,
                                  batch, Wout, bout, out_p, hidden_p, N);
}